// Round 5
// baseline (260.507 us; speedup 1.0000x reference)
//
#include <hip/hip_runtime.h>

constexpr int Bc = 4, Nc = 16384, Mc = 4096, Kc = 32;
constexpr float EPSc = 1e-5f;
constexpr float L2E = 1.4426950408889634f;   // log2(e)

using bf16x8 = __attribute__((ext_vector_type(8))) short;   // 8 bf16 (4 VGPRs)
using f32x4  = __attribute__((ext_vector_type(4))) float;   // 4 fp32

__device__ inline unsigned f2bf_bits(float x) {
    unsigned u = __float_as_uint(x);
    return (u + 0x7fffu + ((u >> 16) & 1u)) >> 16;
}
__device__ inline short f2bf(float x) { return (short)f2bf_bits(x); }

// ---------------------------------------------------------------------------
// pt_prep (1 block): bake scaled+transposed bf16 weights and folded BN
// vectors into ws. WfaT[c][k] (c<64: feat plane * log2e, c>=64: attn plane),
// WrT[c][k], bis_enc[128], bisg[128], cw[64]={w0,w1,w2,P}.
// ---------------------------------------------------------------------------
__global__ __launch_bounds__(256) void pt_prep(
    const float* __restrict__ Wf, const float* __restrict__ Wa,
    const float* __restrict__ Wr, const float* __restrict__ Wx,
    const float* __restrict__ fg, const float* __restrict__ fb,
    const float* __restrict__ fm, const float* __restrict__ fv,
    const float* __restrict__ ag, const float* __restrict__ ab,
    const float* __restrict__ am, const float* __restrict__ av,
    const float* __restrict__ xg, const float* __restrict__ xb,
    const float* __restrict__ xm, const float* __restrict__ xv,
    const float* __restrict__ rg, const float* __restrict__ rb,
    const float* __restrict__ rm, const float* __restrict__ rv,
    short* __restrict__ WfaT, short* __restrict__ WrT,
    float* __restrict__ bis_enc, float* __restrict__ bisg,
    float* __restrict__ cw)
{
    __shared__ float sE[128], sR[128];
    const int tid = threadIdx.x;
    if (tid < 128) {
        const int c = tid & 63;
        const float g  = (tid < 64) ? fg[c] : ag[c];
        const float v  = (tid < 64) ? fv[c] : av[c];
        const float bb = (tid < 64) ? fb[c] : ab[c];
        const float mm = (tid < 64) ? fm[c] : am[c];
        float s = g * rsqrtf(v + EPSc);
        float bi = bb - mm * s;
        if (tid < 64) { s *= L2E; bi *= L2E; }       // feat plane in exp2 domain
        sE[tid] = s;  bis_enc[tid] = bi;
        const float sr = rg[tid] * rsqrtf(rv[tid] + EPSc);
        sR[tid] = sr; bisg[tid] = rb[tid] - rm[tid] * sr;
    }
    if (tid < 64) {
        const float xs = xg[tid] * rsqrtf(xv[tid] + EPSc);
        *(float4*)(cw + tid * 4) = make_float4(
            Wx[tid] * xs, Wx[64 + tid] * xs, Wx[128 + tid] * xs,
            xb[tid] - xm[tid] * xs);
    }
    __syncthreads();
    for (int i = tid; i < 8192; i += 256) {
        const int c = i >> 6, k = i & 63;            // [c][k]
        const float wv = (c < 64) ? Wf[k * 64 + c] : Wa[k * 64 + (c - 64)];
        WfaT[i] = f2bf(wv * sE[c]);
        WrT[i]  = f2bf(Wr[k * 128 + c] * sR[c]);
    }
}

// ---------------------------------------------------------------------------
// pt_encode2 (MFMA, no LDS): Sfa[n][c] = pack(hi=f*log2e, lo=a) as bf16.
// B fragments straight from the prepped 16 KB WfaT (L1/L2-hot).
// ---------------------------------------------------------------------------
template<int REPS>
__global__ __launch_bounds__(256) void pt_encode2(
    const float* __restrict__ feats, const short* __restrict__ WfaT,
    const float* __restrict__ bis_enc, unsigned* __restrict__ Sfa)
{
    const int tid = threadIdx.x, lane = tid & 63, w = tid >> 6;
    const int row16 = lane & 15, kg = lane >> 4;

    for (int rep = 0; rep < REPS; ++rep) {
        const float* fp = feats; const short* wp = WfaT;
        const float* bp = bis_enc; unsigned* op = Sfa;
        if constexpr (REPS > 1)
            asm volatile("" : "+s"(fp), "+s"(wp), "+s"(bp), "+s"(op));

        bf16x8 bfr[8][2];
#pragma unroll
        for (int t = 0; t < 8; ++t)
#pragma unroll
            for (int h = 0; h < 2; ++h)
                bfr[t][h] = *(const bf16x8*)(wp + (16 * t + row16) * 64 + 32 * h + kg * 8);

        const long long base = ((long long)blockIdx.x * 4 + w) * 16;
        const float* arow = fp + (base + row16) * 64 + kg * 8;
        const float4 v0 = *(const float4*)(arow + 0);
        const float4 v1 = *(const float4*)(arow + 4);
        const float4 v2 = *(const float4*)(arow + 32);
        const float4 v3 = *(const float4*)(arow + 36);
        bf16x8 af0, af1;
        af0[0]=f2bf(v0.x); af0[1]=f2bf(v0.y); af0[2]=f2bf(v0.z); af0[3]=f2bf(v0.w);
        af0[4]=f2bf(v1.x); af0[5]=f2bf(v1.y); af0[6]=f2bf(v1.z); af0[7]=f2bf(v1.w);
        af1[0]=f2bf(v2.x); af1[1]=f2bf(v2.y); af1[2]=f2bf(v2.z); af1[3]=f2bf(v2.w);
        af1[4]=f2bf(v3.x); af1[5]=f2bf(v3.y); af1[6]=f2bf(v3.z); af1[7]=f2bf(v3.w);

        f32x4 acc[8];
#pragma unroll
        for (int t = 0; t < 8; ++t) {
            f32x4 z = {0.f, 0.f, 0.f, 0.f};
            z = __builtin_amdgcn_mfma_f32_16x16x32_bf16(af0, bfr[t][0], z, 0, 0, 0);
            z = __builtin_amdgcn_mfma_f32_16x16x32_bf16(af1, bfr[t][1], z, 0, 0, 0);
            acc[t] = z;
        }
        // C/D layout: row=(lane>>4)*4+reg, col=lane&15
#pragma unroll
        for (int t = 0; t < 4; ++t) {
            const int c = 16 * t + row16;
            const float bfv = bp[c], bav = bp[64 + c];
#pragma unroll
            for (int r = 0; r < 4; ++r) {
                const unsigned u = f2bf_bits(acc[t + 4][r] + bav)
                                 | (f2bf_bits(acc[t][r] + bfv) << 16);
                op[(base + kg * 4 + r) * 64 + c] = u;
            }
        }
    }
}

// ---------------------------------------------------------------------------
// pt_gr2: 8 waves, 1 group/wave. 32 gathers prefetched to registers; xyz-proj
// coeffs from prepped cw; refine B-frags from prepped WrT (no WT LDS at all).
// Nontemporal gidx loads and out stores protect Sfa's L2 residency.
// ---------------------------------------------------------------------------
template<int REPS>
__global__ __launch_bounds__(512, 6) void pt_gr2(
    const float* __restrict__ xyz, const float* __restrict__ nxyz,
    const unsigned* __restrict__ Sfa, const short* __restrict__ WrT,
    const float* __restrict__ bisg, const float* __restrict__ cw,
    const int* __restrict__ gidx, const int* __restrict__ gcnt,
    float* __restrict__ out)
{
    __shared__ __align__(16) short snf[16][72];   // rows 0-7 groups, 8-15 zero
    __shared__ int    sidx[8][32];
    __shared__ float4 sxyz[8][32];

    const int tid = threadIdx.x, lane = tid & 63, w = tid >> 6;
    const int row16 = lane & 15, kg = lane >> 4;
    // bijective XCD-pinning swizzle: xcd = blk%8 serves batch (blk%8)>>1
    const int i = blockIdx.x;                     // 0..2047
    const int b = (i & 7) >> 1;
    const int j = ((i >> 3) << 1) | (i & 1);      // 0..511
    const long long gbase = (long long)b * Mc + j * 8;

    for (int rep = 0; rep < REPS; ++rep) {
        const float* xyzp = xyz; const float* nxp = nxyz;
        const unsigned* sfap = Sfa; const short* wrp = WrT;
        const float* bgp = bisg; const float* cwp = cw;
        const int* gip = gidx; float* op = out;
        if constexpr (REPS > 1)
            asm volatile("" : "+s"(xyzp), "+s"(nxp), "+s"(sfap), "+s"(wrp),
                              "+s"(bgp), "+s"(cwp), "+s"(gip), "+s"(op));

        if (tid < 256) {   // stage neighbor idx + xyz: one (group,k)/thread
            const int gi = tid >> 5, kk = tid & 31;
            const int n = __builtin_nontemporal_load(gip + (gbase + gi) * 32 + kk);
            sidx[gi][kk] = n;
            const float* xp = xyzp + ((long long)b * Nc + n) * 3;
            sxyz[gi][kk] = make_float4(xp[0], xp[1], xp[2], 0.f);
        }
        __syncthreads();

        // issue all 32 gathers (SGPR row base + lane offset)
        const unsigned* sbase = sfap + (long long)b * (Nc * 64);
        unsigned d[32];
#pragma unroll
        for (int k = 0; k < Kc; ++k) {
            const int n = __builtin_amdgcn_readfirstlane(sidx[w][k]);
            d[k] = sbase[((long long)n << 6) + lane];
        }

        const float4 cwl = *(const float4*)(cwp + lane * 4);  // w0,w1,w2,P
        const float* nx = nxp + (gbase + w) * 3;
        const float Q = cwl.w - fmaf(nx[0], cwl.x, fmaf(nx[1], cwl.y, nx[2] * cwl.z));

        float ss = 0.f, ac = 0.f;
#pragma unroll
        for (int k = 0; k < Kc; ++k) {
            const float4 x = sxyz[w][k];              // LDS broadcast
            const float gx = fmaf(x.x, cwl.x, fmaf(x.y, cwl.y, fmaf(x.z, cwl.z, Q)));
            const float e = __builtin_amdgcn_exp2f(
                fmaf(gx, L2E, __uint_as_float(d[k] & 0xffff0000u)));
            const float a = __uint_as_float(d[k] << 16) + gx;
            ss += e;
            ac = fmaf(e, a, ac);
        }
        snf[w][lane] = f2bf(ac / ss);
        snf[8 + w][lane] = 0;
        __syncthreads();

        // refine MFMA: A = snf (8 valid rows), B = WrT col-tile w (global, hot)
        const bf16x8 af0 = *(const bf16x8*)&snf[row16][kg * 8];
        const bf16x8 af1 = *(const bf16x8*)&snf[row16][32 + kg * 8];
        const bf16x8 bf0 = *(const bf16x8*)(wrp + (16 * w + row16) * 64 + kg * 8);
        const bf16x8 bf1 = *(const bf16x8*)(wrp + (16 * w + row16) * 64 + 32 + kg * 8);
        f32x4 z = {0.f, 0.f, 0.f, 0.f};
        z = __builtin_amdgcn_mfma_f32_16x16x32_bf16(af0, bf0, z, 0, 0, 0);
        z = __builtin_amdgcn_mfma_f32_16x16x32_bf16(af1, bf1, z, 0, 0, 0);

        if (kg < 2) {                                 // rows 0-7 are real groups
            const int4 c4 = *(const int4*)(gcnt + gbase + kg * 4);
            const int cc = 16 * w + row16;
            const float bb = bgp[cc];
            float* orow = op + (gbase + kg * 4) * 128 + cc;
            __builtin_nontemporal_store(fmaxf(z[0] + bb, 0.f) * (c4.x > 0 ? 1.f : 0.f), orow);
            __builtin_nontemporal_store(fmaxf(z[1] + bb, 0.f) * (c4.y > 0 ? 1.f : 0.f), orow + 128);
            __builtin_nontemporal_store(fmaxf(z[2] + bb, 0.f) * (c4.z > 0 ? 1.f : 0.f), orow + 256);
            __builtin_nontemporal_store(fmaxf(z[3] + bb, 0.f) * (c4.w > 0 ? 1.f : 0.f), orow + 384);
        }
        __syncthreads();   // LDS reuse across reps (harmless for REPS==1)
    }
}

extern "C" void kernel_launch(void* const* d_in, const int* in_sizes, int n_in,
                              void* d_out, int out_size, void* d_ws, size_t ws_size,
                              hipStream_t stream)
{
    const float* xyz  = (const float*)d_in[0];
    const float* nxyz = (const float*)d_in[1];
    const float* feats = (const float*)d_in[2];
    const float* Wf = (const float*)d_in[3];
    const float* fg = (const float*)d_in[4];
    const float* fb = (const float*)d_in[5];
    const float* fm = (const float*)d_in[6];
    const float* fv = (const float*)d_in[7];
    const float* Wa = (const float*)d_in[8];
    const float* ag = (const float*)d_in[9];
    const float* ab = (const float*)d_in[10];
    const float* am = (const float*)d_in[11];
    const float* av = (const float*)d_in[12];
    const float* Wx = (const float*)d_in[13];
    const float* xg = (const float*)d_in[14];
    const float* xb = (const float*)d_in[15];
    const float* xm = (const float*)d_in[16];
    const float* xv = (const float*)d_in[17];
    const float* Wr = (const float*)d_in[18];
    const float* rg = (const float*)d_in[19];
    const float* rb = (const float*)d_in[20];
    const float* rm = (const float*)d_in[21];
    const float* rv = (const float*)d_in[22];
    const int* gidx = (const int*)d_in[23];
    const int* gcnt = (const int*)d_in[24];
    float* out = (float*)d_out;

    char* ws = (char*)d_ws;
    const size_t SFA_B = (size_t)Bc * Nc * 64 * 4;       // 16 MiB
    unsigned* Sfa  = (unsigned*)ws;
    short* WfaT    = (short*)(ws + SFA_B);
    short* WrT     = (short*)(ws + SFA_B + 16384);
    float* bis_enc = (float*)(ws + SFA_B + 32768);
    float* bisg    = (float*)(ws + SFA_B + 33280);
    float* cw      = (float*)(ws + SFA_B + 33792);
    unsigned* Sfa2 = (unsigned*)(ws + (32u << 20));      // diag scratch
    float* out2    = (float*)(ws + (64u << 20));

    pt_prep<<<dim3(1), dim3(256), 0, stream>>>(
        Wf, Wa, Wr, Wx, fg, fb, fm, fv, ag, ab, am, av,
        xg, xb, xm, xv, rg, rb, rm, rv, WfaT, WrT, bis_enc, bisg, cw);
    pt_encode2<1><<<dim3((Bc * Nc / 16) / 4), dim3(256), 0, stream>>>(
        feats, WfaT, bis_enc, Sfa);
    pt_gr2<1><<<dim3((Bc * Mc) / 8), dim3(512), 0, stream>>>(
        xyz, nxyz, Sfa, WrT, bisg, cw, gidx, gcnt, out);

    // ---- diagnostic repeats (write to ws scratch; visibility into counters) ----
    pt_encode2<10><<<dim3((Bc * Nc / 16) / 4), dim3(256), 0, stream>>>(
        feats, WfaT, bis_enc, Sfa2);
    pt_gr2<6><<<dim3((Bc * Mc) / 8), dim3(512), 0, stream>>>(
        xyz, nxyz, Sfa, WrT, bisg, cw, gidx, gcnt, out2);
}

// Round 6
// 48.171 us; speedup vs baseline: 5.4080x; 5.4080x over previous
//
#include <hip/hip_runtime.h>

constexpr int Bc = 4, Nc = 16384, Mc = 4096, Kc = 32;
constexpr float EPSc = 1e-5f;
constexpr float L2E = 1.4426950408889634f;   // log2(e)

using bf16x8 = __attribute__((ext_vector_type(8))) short;   // 8 bf16 (4 VGPRs)
using f32x4  = __attribute__((ext_vector_type(4))) float;   // 4 fp32

__device__ inline unsigned f2bf_bits(float x) {
    unsigned u = __float_as_uint(x);
    return (u + 0x7fffu + ((u >> 16) & 1u)) >> 16;
}
__device__ inline short f2bf(float x) { return (short)f2bf_bits(x); }

// ---------------------------------------------------------------------------
// pt_prep (32 blocks): bake scaled+transposed bf16 weights and folded BN
// vectors into ws. WfaT[c][k] (c<64: feat plane * log2e, c>=64: attn plane),
// WrT[c][k], bis_enc[128], bisg[128], cw[64]={w0,w1,w2,P}.
// ---------------------------------------------------------------------------
__global__ __launch_bounds__(256) void pt_prep(
    const float* __restrict__ Wf, const float* __restrict__ Wa,
    const float* __restrict__ Wr, const float* __restrict__ Wx,
    const float* __restrict__ fg, const float* __restrict__ fb,
    const float* __restrict__ fm, const float* __restrict__ fv,
    const float* __restrict__ ag, const float* __restrict__ ab,
    const float* __restrict__ am, const float* __restrict__ av,
    const float* __restrict__ xg, const float* __restrict__ xb,
    const float* __restrict__ xm, const float* __restrict__ xv,
    const float* __restrict__ rg, const float* __restrict__ rb,
    const float* __restrict__ rm, const float* __restrict__ rv,
    short* __restrict__ WfaT, short* __restrict__ WrT,
    float* __restrict__ bis_enc, float* __restrict__ bisg,
    float* __restrict__ cw)
{
    __shared__ float sE[128], sR[128];
    const int tid = threadIdx.x;
    if (tid < 128) {
        const int c = tid & 63;
        const float g  = (tid < 64) ? fg[c] : ag[c];
        const float v  = (tid < 64) ? fv[c] : av[c];
        const float bb = (tid < 64) ? fb[c] : ab[c];
        const float mm = (tid < 64) ? fm[c] : am[c];
        float s = g * rsqrtf(v + EPSc);
        float bi = bb - mm * s;
        if (tid < 64) { s *= L2E; bi *= L2E; }       // feat plane in exp2 domain
        sE[tid] = s;
        const float sr = rg[tid] * rsqrtf(rv[tid] + EPSc);
        sR[tid] = sr;
        if (blockIdx.x == 0) {
            bis_enc[tid] = bi;
            bisg[tid] = rb[tid] - rm[tid] * sr;
        }
    }
    if (blockIdx.x == 0 && tid < 64) {
        const float xs = xg[tid] * rsqrtf(xv[tid] + EPSc);
        *(float4*)(cw + tid * 4) = make_float4(
            Wx[tid] * xs, Wx[64 + tid] * xs, Wx[128 + tid] * xs,
            xb[tid] - xm[tid] * xs);
    }
    __syncthreads();
    const int i = blockIdx.x * 256 + tid;            // 0..8191
    const int c = i >> 6, k = i & 63;                // [c][k]
    const float wv = (c < 64) ? Wf[k * 64 + c] : Wa[k * 64 + (c - 64)];
    WfaT[i] = f2bf(wv * sE[c]);
    WrT[i]  = f2bf(Wr[k * 128 + c] * sR[c]);
}

// ---------------------------------------------------------------------------
// pt_encode2 (MFMA): Sfa[n][c] = pack(hi=f*log2e, lo=a) as bf16.
// B fragments from the prepped 16 KB WfaT (L1/L2-hot). C-write goes through
// an LDS transpose tile so global stores are 16 fully-coalesced 256B rows.
// ---------------------------------------------------------------------------
__global__ __launch_bounds__(256) void pt_encode2(
    const float* __restrict__ feats, const short* __restrict__ WfaT,
    const float* __restrict__ bis_enc, unsigned* __restrict__ Sfa)
{
    __shared__ unsigned stile[4][16][68];            // [wave][row][col], 2-way max
    const int tid = threadIdx.x, lane = tid & 63, w = tid >> 6;
    const int row16 = lane & 15, kg = lane >> 4;

    bf16x8 bfr[8][2];
#pragma unroll
    for (int t = 0; t < 8; ++t)
#pragma unroll
        for (int h = 0; h < 2; ++h)
            bfr[t][h] = *(const bf16x8*)(WfaT + (16 * t + row16) * 64 + 32 * h + kg * 8);

    const long long base = ((long long)blockIdx.x * 4 + w) * 16;
    const float* arow = feats + (base + row16) * 64 + kg * 8;
    const float4 v0 = *(const float4*)(arow + 0);
    const float4 v1 = *(const float4*)(arow + 4);
    const float4 v2 = *(const float4*)(arow + 32);
    const float4 v3 = *(const float4*)(arow + 36);
    bf16x8 af0, af1;
    af0[0]=f2bf(v0.x); af0[1]=f2bf(v0.y); af0[2]=f2bf(v0.z); af0[3]=f2bf(v0.w);
    af0[4]=f2bf(v1.x); af0[5]=f2bf(v1.y); af0[6]=f2bf(v1.z); af0[7]=f2bf(v1.w);
    af1[0]=f2bf(v2.x); af1[1]=f2bf(v2.y); af1[2]=f2bf(v2.z); af1[3]=f2bf(v2.w);
    af1[4]=f2bf(v3.x); af1[5]=f2bf(v3.y); af1[6]=f2bf(v3.z); af1[7]=f2bf(v3.w);

    f32x4 acc[8];
#pragma unroll
    for (int t = 0; t < 8; ++t) {
        f32x4 z = {0.f, 0.f, 0.f, 0.f};
        z = __builtin_amdgcn_mfma_f32_16x16x32_bf16(af0, bfr[t][0], z, 0, 0, 0);
        z = __builtin_amdgcn_mfma_f32_16x16x32_bf16(af1, bfr[t][1], z, 0, 0, 0);
        acc[t] = z;
    }
    // C/D layout: row=(lane>>4)*4+reg, col=lane&15 -> LDS tile -> coalesced
#pragma unroll
    for (int t = 0; t < 4; ++t) {
        const int c = 16 * t + row16;
        const float bfv = bis_enc[c], bav = bis_enc[64 + c];
#pragma unroll
        for (int r = 0; r < 4; ++r)
            stile[w][kg * 4 + r][c] = f2bf_bits(acc[t + 4][r] + bav)
                                    | (f2bf_bits(acc[t][r] + bfv) << 16);
    }
    __syncthreads();
#pragma unroll
    for (int rr = 0; rr < 16; ++rr)
        Sfa[(base + rr) * 64 + lane] = stile[w][rr][lane];
}

// ---------------------------------------------------------------------------
// pt_gr3: 8 waves, 1 group/wave, per-wave staging. All 32 gathers forced
// in-flight (sched_barrier fence + launch_bounds VGPR room), then exp2-domain
// softmax, snf -> LDS, 8-row refine MFMA + BN/ReLU/mask, coalesced-ish store.
// Block swizzle pins batch b to XCD pair {2b,2b+1} (~4 MB working set/XCD).
// ---------------------------------------------------------------------------
__global__ __launch_bounds__(512, 4) void pt_gr3(
    const float* __restrict__ xyz, const float* __restrict__ nxyz,
    const unsigned* __restrict__ Sfa, const short* __restrict__ WrT,
    const float* __restrict__ bisg, const float* __restrict__ cw,
    const int* __restrict__ gidx, const int* __restrict__ gcnt,
    float* __restrict__ out)
{
    __shared__ __align__(16) short snf[16][72];   // rows 0-7 groups, 8-15 zero
    __shared__ int    sidx[8][32];
    __shared__ float4 sxyz[8][32];

    const int tid = threadIdx.x, lane = tid & 63, w = tid >> 6;
    const int row16 = lane & 15, kg = lane >> 4;
    // bijective XCD-pinning swizzle: xcd = blk%8 serves batch (blk%8)>>1
    const int i = blockIdx.x;                     // 0..2047
    const int b = (i & 7) >> 1;
    const int j = ((i >> 3) << 1) | (i & 1);      // 0..511
    const long long gbase = (long long)b * Mc + j * 8;

    if (lane < 32) {   // per-wave staging of own group's idx + xyz
        const int n = __builtin_nontemporal_load(gidx + (gbase + w) * 32 + lane);
        sidx[w][lane] = n;
        const float* xp = xyz + ((long long)b * Nc + n) * 3;
        sxyz[w][lane] = make_float4(xp[0], xp[1], xp[2], 0.f);
    }
    __syncthreads();

    // per-lane channel coeffs + group constant (issue early, L1-hot)
    const float4 cwl = *(const float4*)(cw + lane * 4);  // w0,w1,w2,P
    const float* nx = nxyz + (gbase + w) * 3;
    const float Q = cwl.w - fmaf(nx[0], cwl.x, fmaf(nx[1], cwl.y, nx[2] * cwl.z));

    // issue ALL 32 gathers (SGPR row base via readfirstlane + lane offset)
    const unsigned* sbase = Sfa + (long long)b * (Nc * 64);
    unsigned d[32];
#pragma unroll
    for (int k = 0; k < Kc; ++k) {
        const int n = __builtin_amdgcn_readfirstlane(sidx[w][k]);
        d[k] = sbase[(n << 6) + lane];
    }
    __builtin_amdgcn_sched_barrier(0);            // keep loads ahead of consume

    float ss = 0.f, ac = 0.f;
#pragma unroll
    for (int k = 0; k < Kc; ++k) {
        const float4 x = sxyz[w][k];              // LDS broadcast
        const float gx = fmaf(x.x, cwl.x, fmaf(x.y, cwl.y, fmaf(x.z, cwl.z, Q)));
        const float e = __builtin_amdgcn_exp2f(
            fmaf(gx, L2E, __uint_as_float(d[k] & 0xffff0000u)));
        const float a = __uint_as_float(d[k] << 16) + gx;
        ss += e;
        ac = fmaf(e, a, ac);
    }
    snf[w][lane] = f2bf(ac * __builtin_amdgcn_rcpf(ss));
    snf[8 + w][lane] = 0;
    __syncthreads();

    // refine MFMA: A = snf (8 valid rows), B = WrT col-tile w (global, hot)
    const bf16x8 af0 = *(const bf16x8*)&snf[row16][kg * 8];
    const bf16x8 af1 = *(const bf16x8*)&snf[row16][32 + kg * 8];
    const bf16x8 bf0 = *(const bf16x8*)(WrT + (16 * w + row16) * 64 + kg * 8);
    const bf16x8 bf1 = *(const bf16x8*)(WrT + (16 * w + row16) * 64 + 32 + kg * 8);
    f32x4 z = {0.f, 0.f, 0.f, 0.f};
    z = __builtin_amdgcn_mfma_f32_16x16x32_bf16(af0, bf0, z, 0, 0, 0);
    z = __builtin_amdgcn_mfma_f32_16x16x32_bf16(af1, bf1, z, 0, 0, 0);

    if (kg < 2) {                                 // rows 0-7 are real groups
        const int4 c4 = *(const int4*)(gcnt + gbase + kg * 4);
        const int cc = 16 * w + row16;
        const float bb = bisg[cc];
        float* orow = out + (gbase + kg * 4) * 128 + cc;
        __builtin_nontemporal_store(fmaxf(z[0] + bb, 0.f) * (c4.x > 0 ? 1.f : 0.f), orow);
        __builtin_nontemporal_store(fmaxf(z[1] + bb, 0.f) * (c4.y > 0 ? 1.f : 0.f), orow + 128);
        __builtin_nontemporal_store(fmaxf(z[2] + bb, 0.f) * (c4.z > 0 ? 1.f : 0.f), orow + 256);
        __builtin_nontemporal_store(fmaxf(z[3] + bb, 0.f) * (c4.w > 0 ? 1.f : 0.f), orow + 384);
    }
}

extern "C" void kernel_launch(void* const* d_in, const int* in_sizes, int n_in,
                              void* d_out, int out_size, void* d_ws, size_t ws_size,
                              hipStream_t stream)
{
    const float* xyz  = (const float*)d_in[0];
    const float* nxyz = (const float*)d_in[1];
    const float* feats = (const float*)d_in[2];
    const float* Wf = (const float*)d_in[3];
    const float* fg = (const float*)d_in[4];
    const float* fb = (const float*)d_in[5];
    const float* fm = (const float*)d_in[6];
    const float* fv = (const float*)d_in[7];
    const float* Wa = (const float*)d_in[8];
    const float* ag = (const float*)d_in[9];
    const float* ab = (const float*)d_in[10];
    const float* am = (const float*)d_in[11];
    const float* av = (const float*)d_in[12];
    const float* Wx = (const float*)d_in[13];
    const float* xg = (const float*)d_in[14];
    const float* xb = (const float*)d_in[15];
    const float* xm = (const float*)d_in[16];
    const float* xv = (const float*)d_in[17];
    const float* Wr = (const float*)d_in[18];
    const float* rg = (const float*)d_in[19];
    const float* rb = (const float*)d_in[20];
    const float* rm = (const float*)d_in[21];
    const float* rv = (const float*)d_in[22];
    const int* gidx = (const int*)d_in[23];
    const int* gcnt = (const int*)d_in[24];
    float* out = (float*)d_out;

    char* ws = (char*)d_ws;
    const size_t SFA_B = (size_t)Bc * Nc * 64 * 4;       // 16 MiB
    unsigned* Sfa  = (unsigned*)ws;
    short* WfaT    = (short*)(ws + SFA_B);
    short* WrT     = (short*)(ws + SFA_B + 16384);
    float* bis_enc = (float*)(ws + SFA_B + 32768);
    float* bisg    = (float*)(ws + SFA_B + 33280);
    float* cw      = (float*)(ws + SFA_B + 33792);

    pt_prep<<<dim3(32), dim3(256), 0, stream>>>(
        Wf, Wa, Wr, Wx, fg, fb, fm, fv, ag, ab, am, av,
        xg, xb, xm, xv, rg, rb, rm, rv, WfaT, WrT, bis_enc, bisg, cw);
    pt_encode2<<<dim3((Bc * Nc / 16) / 4), dim3(256), 0, stream>>>(
        feats, WfaT, bis_enc, Sfa);
    pt_gr3<<<dim3((Bc * Mc) / 8), dim3(512), 0, stream>>>(
        xyz, nxyz, Sfa, WrT, bisg, cw, gidx, gcnt, out);
}

// Round 7
// 44.270 us; speedup vs baseline: 5.8845x; 1.0881x over previous
//
#include <hip/hip_runtime.h>

constexpr int Bc = 4, Nc = 16384, Mc = 4096, Kc = 32;
constexpr float EPSc = 1e-5f;
constexpr float L2E = 1.4426950408889634f;   // log2(e)

using bf16x8 = __attribute__((ext_vector_type(8))) short;   // 8 bf16 (4 VGPRs)
using f32x4  = __attribute__((ext_vector_type(4))) float;   // 4 fp32

__device__ inline unsigned f2bf_bits(float x) {
    unsigned u = __float_as_uint(x);
    return (u + 0x7fffu + ((u >> 16) & 1u)) >> 16;
}
__device__ inline short f2bf(float x) { return (short)f2bf_bits(x); }

// ---------------------------------------------------------------------------
// pt_prep (32 blocks): bake scaled+transposed bf16 weights and folded BN
// vectors into ws. WfaT[c][k] (c<64: feat plane * log2e, c>=64: attn plane),
// WrT[c][k], bis_enc[128], bisg[128], cw[64]={w0,w1,w2,P} (w = Wx col * BNscale).
// ---------------------------------------------------------------------------
__global__ __launch_bounds__(256) void pt_prep(
    const float* __restrict__ Wf, const float* __restrict__ Wa,
    const float* __restrict__ Wr, const float* __restrict__ Wx,
    const float* __restrict__ fg, const float* __restrict__ fb,
    const float* __restrict__ fm, const float* __restrict__ fv,
    const float* __restrict__ ag, const float* __restrict__ ab,
    const float* __restrict__ am, const float* __restrict__ av,
    const float* __restrict__ xg, const float* __restrict__ xb,
    const float* __restrict__ xm, const float* __restrict__ xv,
    const float* __restrict__ rg, const float* __restrict__ rb,
    const float* __restrict__ rm, const float* __restrict__ rv,
    short* __restrict__ WfaT, short* __restrict__ WrT,
    float* __restrict__ bis_enc, float* __restrict__ bisg,
    float* __restrict__ cw)
{
    __shared__ float sE[128], sR[128];
    const int tid = threadIdx.x;
    if (tid < 128) {
        const int c = tid & 63;
        const float g  = (tid < 64) ? fg[c] : ag[c];
        const float v  = (tid < 64) ? fv[c] : av[c];
        const float bb = (tid < 64) ? fb[c] : ab[c];
        const float mm = (tid < 64) ? fm[c] : am[c];
        float s = g * rsqrtf(v + EPSc);
        float bi = bb - mm * s;
        if (tid < 64) { s *= L2E; bi *= L2E; }       // feat plane in exp2 domain
        sE[tid] = s;
        const float sr = rg[tid] * rsqrtf(rv[tid] + EPSc);
        sR[tid] = sr;
        if (blockIdx.x == 0) {
            bis_enc[tid] = bi;
            bisg[tid] = rb[tid] - rm[tid] * sr;
        }
    }
    if (blockIdx.x == 0 && tid < 64) {
        const float xs = xg[tid] * rsqrtf(xv[tid] + EPSc);
        *(float4*)(cw + tid * 4) = make_float4(
            Wx[tid] * xs, Wx[64 + tid] * xs, Wx[128 + tid] * xs,
            xb[tid] - xm[tid] * xs);
    }
    __syncthreads();
    const int i = blockIdx.x * 256 + tid;            // 0..8191
    const int c = i >> 6, k = i & 63;                // [c][k]
    const float wv = (c < 64) ? Wf[k * 64 + c] : Wa[k * 64 + (c - 64)];
    WfaT[i] = f2bf(wv * sE[c]);
    WrT[i]  = f2bf(Wr[k * 128 + c] * sR[c]);
}

// ---------------------------------------------------------------------------
// pt_encode3 (MFMA): Sfa[n][c] = pack( hi = bf16((f_bn + dot(x_n,w_c))*log2e),
//                                      lo = bf16(a_bn + dot(x_n,w_c)) )
// The NEIGHBOR part of the xyz projection is folded here (per-point linear
// term), so phase B needs no xyz gather/staging at all. C-write goes through
// an LDS transpose tile -> 16 fully-coalesced 256B row stores per wave.
// ---------------------------------------------------------------------------
__global__ __launch_bounds__(256) void pt_encode3(
    const float* __restrict__ feats, const float* __restrict__ xyz,
    const short* __restrict__ WfaT, const float* __restrict__ bis_enc,
    const float* __restrict__ cw, unsigned* __restrict__ Sfa)
{
    __shared__ unsigned stile[4][16][68];            // [wave][row][col]
    __shared__ float sx[64][3];                      // block's 64 points' xyz
    const int tid = threadIdx.x, lane = tid & 63, w = tid >> 6;
    const int row16 = lane & 15, kg = lane >> 4;

    const long long row0 = (long long)blockIdx.x * 64;
    if (tid < 192) ((float*)sx)[tid] = xyz[row0 * 3 + tid];

    bf16x8 bfr[8][2];
#pragma unroll
    for (int t = 0; t < 8; ++t)
#pragma unroll
        for (int h = 0; h < 2; ++h)
            bfr[t][h] = *(const bf16x8*)(WfaT + (16 * t + row16) * 64 + 32 * h + kg * 8);

    const long long base = row0 + w * 16;
    const float* arow = feats + (base + row16) * 64 + kg * 8;
    const float4 v0 = *(const float4*)(arow + 0);
    const float4 v1 = *(const float4*)(arow + 4);
    const float4 v2 = *(const float4*)(arow + 32);
    const float4 v3 = *(const float4*)(arow + 36);
    bf16x8 af0, af1;
    af0[0]=f2bf(v0.x); af0[1]=f2bf(v0.y); af0[2]=f2bf(v0.z); af0[3]=f2bf(v0.w);
    af0[4]=f2bf(v1.x); af0[5]=f2bf(v1.y); af0[6]=f2bf(v1.z); af0[7]=f2bf(v1.w);
    af1[0]=f2bf(v2.x); af1[1]=f2bf(v2.y); af1[2]=f2bf(v2.z); af1[3]=f2bf(v2.w);
    af1[4]=f2bf(v3.x); af1[5]=f2bf(v3.y); af1[6]=f2bf(v3.z); af1[7]=f2bf(v3.w);

    f32x4 acc[8];
#pragma unroll
    for (int t = 0; t < 8; ++t) {
        f32x4 z = {0.f, 0.f, 0.f, 0.f};
        z = __builtin_amdgcn_mfma_f32_16x16x32_bf16(af0, bfr[t][0], z, 0, 0, 0);
        z = __builtin_amdgcn_mfma_f32_16x16x32_bf16(af1, bfr[t][1], z, 0, 0, 0);
        acc[t] = z;
    }
    __syncthreads();                                 // sx visible to all waves

    // per-lane xyz-proj coeffs for this lane's 4 output cols
    float4 cwt[4];
#pragma unroll
    for (int t = 0; t < 4; ++t)
        cwt[t] = *(const float4*)(cw + (16 * t + row16) * 4);

    const int lrow = w * 16 + kg * 4;
    // C/D layout: row=(lane>>4)*4+reg, col=lane&15 -> LDS tile -> coalesced
#pragma unroll
    for (int r = 0; r < 4; ++r) {
        const float x0 = sx[lrow + r][0], x1 = sx[lrow + r][1], x2 = sx[lrow + r][2];
#pragma unroll
        for (int t = 0; t < 4; ++t) {
            const int c = 16 * t + row16;
            const float px = fmaf(x0, cwt[t].x, fmaf(x1, cwt[t].y, x2 * cwt[t].z));
            stile[w][kg * 4 + r][c] =
                  f2bf_bits(acc[t + 4][r] + bis_enc[64 + c] + px)
                | (f2bf_bits(acc[t][r] + bis_enc[c] + px * L2E) << 16);
        }
    }
    __syncthreads();
#pragma unroll
    for (int rr = 0; rr < 16; ++rr)
        Sfa[(base + rr) * 64 + lane] = stile[w][rr][lane];
}

// ---------------------------------------------------------------------------
// pt_gr4: 8 waves, 1 group/wave. Inner loop is 4 VALU + exp per k (xyz fully
// folded into Sfa); 32 gathers via SGPR base + lane offset; snf -> LDS,
// 8-row refine MFMA + BN/ReLU/mask. XCD-pinned block swizzle (batch -> XCD pair).
// ---------------------------------------------------------------------------
__global__ __launch_bounds__(512, 6) void pt_gr4(
    const float* __restrict__ nxyz, const unsigned* __restrict__ Sfa,
    const short* __restrict__ WrT, const float* __restrict__ bisg,
    const float* __restrict__ cw, const int* __restrict__ gidx,
    const int* __restrict__ gcnt, float* __restrict__ out)
{
    __shared__ __align__(16) short snf[16][72];   // rows 0-7 groups, 8-15 zero
    __shared__ int sidx[8][32];

    const int tid = threadIdx.x, lane = tid & 63, w = tid >> 6;
    const int row16 = lane & 15, kg = lane >> 4;
    // bijective XCD-pinning swizzle: xcd = blk%8 serves batch (blk%8)>>1
    const int i = blockIdx.x;                     // 0..2047
    const int b = (i & 7) >> 1;
    const int j = ((i >> 3) << 1) | (i & 1);      // 0..511
    const long long gbase = (long long)b * Mc + j * 8;

    if (lane < 32) sidx[w][lane] = gidx[(gbase + w) * 32 + lane];  // wave-local

    // per-lane channel coeffs + group constant Q (P - dot(x_m, w))
    const float4 cwl = *(const float4*)(cw + lane * 4);  // w0,w1,w2,P
    const float* nx = nxyz + (gbase + w) * 3;
    const float Q = cwl.w - fmaf(nx[0], cwl.x, fmaf(nx[1], cwl.y, nx[2] * cwl.z));
    const float Ql = Q * L2E;

    // refine B-fragments issued early (L1/L2-hot 16KB table)
    const bf16x8 bf0 = *(const bf16x8*)(WrT + (16 * w + row16) * 64 + kg * 8);
    const bf16x8 bf1 = *(const bf16x8*)(WrT + (16 * w + row16) * 64 + 32 + kg * 8);

    // issue all 32 gathers (SGPR row base via readfirstlane + lane offset)
    const unsigned* sbase = Sfa + (long long)b * (Nc * 64);
    unsigned d[32];
#pragma unroll
    for (int k = 0; k < Kc; ++k) {
        const int n = __builtin_amdgcn_readfirstlane(sidx[w][k]);
        d[k] = sbase[(n << 6) + lane];
    }

    float ss = 0.f, ac = 0.f;
#pragma unroll
    for (int k = 0; k < Kc; ++k) {
        // hi16 = (f+px)*log2e (bf16 bits), lo16 = a+px (bf16 bits)
        const float e = __builtin_amdgcn_exp2f(__uint_as_float(d[k] & 0xffff0000u) + Ql);
        const float a = __uint_as_float(d[k] << 16) + Q;
        ss += e;
        ac = fmaf(e, a, ac);
    }
    snf[w][lane] = f2bf(ac * __builtin_amdgcn_rcpf(ss));
    snf[8 + w][lane] = 0;
    __syncthreads();

    // refine MFMA: A = snf (8 valid rows), B = WrT col-tile w
    const bf16x8 af0 = *(const bf16x8*)&snf[row16][kg * 8];
    const bf16x8 af1 = *(const bf16x8*)&snf[row16][32 + kg * 8];
    f32x4 z = {0.f, 0.f, 0.f, 0.f};
    z = __builtin_amdgcn_mfma_f32_16x16x32_bf16(af0, bf0, z, 0, 0, 0);
    z = __builtin_amdgcn_mfma_f32_16x16x32_bf16(af1, bf1, z, 0, 0, 0);

    if (kg < 2) {                                 // rows 0-7 are real groups
        const int4 c4 = *(const int4*)(gcnt + gbase + kg * 4);
        const int cc = 16 * w + row16;
        const float bb = bisg[cc];
        float* orow = out + (gbase + kg * 4) * 128 + cc;
        __builtin_nontemporal_store(fmaxf(z[0] + bb, 0.f) * (c4.x > 0 ? 1.f : 0.f), orow);
        __builtin_nontemporal_store(fmaxf(z[1] + bb, 0.f) * (c4.y > 0 ? 1.f : 0.f), orow + 128);
        __builtin_nontemporal_store(fmaxf(z[2] + bb, 0.f) * (c4.z > 0 ? 1.f : 0.f), orow + 256);
        __builtin_nontemporal_store(fmaxf(z[3] + bb, 0.f) * (c4.w > 0 ? 1.f : 0.f), orow + 384);
    }
}

extern "C" void kernel_launch(void* const* d_in, const int* in_sizes, int n_in,
                              void* d_out, int out_size, void* d_ws, size_t ws_size,
                              hipStream_t stream)
{
    const float* xyz  = (const float*)d_in[0];
    const float* nxyz = (const float*)d_in[1];
    const float* feats = (const float*)d_in[2];
    const float* Wf = (const float*)d_in[3];
    const float* fg = (const float*)d_in[4];
    const float* fb = (const float*)d_in[5];
    const float* fm = (const float*)d_in[6];
    const float* fv = (const float*)d_in[7];
    const float* Wa = (const float*)d_in[8];
    const float* ag = (const float*)d_in[9];
    const float* ab = (const float*)d_in[10];
    const float* am = (const float*)d_in[11];
    const float* av = (const float*)d_in[12];
    const float* Wx = (const float*)d_in[13];
    const float* xg = (const float*)d_in[14];
    const float* xb = (const float*)d_in[15];
    const float* xm = (const float*)d_in[16];
    const float* xv = (const float*)d_in[17];
    const float* Wr = (const float*)d_in[18];
    const float* rg = (const float*)d_in[19];
    const float* rb = (const float*)d_in[20];
    const float* rm = (const float*)d_in[21];
    const float* rv = (const float*)d_in[22];
    const int* gidx = (const int*)d_in[23];
    const int* gcnt = (const int*)d_in[24];
    float* out = (float*)d_out;

    char* ws = (char*)d_ws;
    const size_t SFA_B = (size_t)Bc * Nc * 64 * 4;       // 16 MiB
    unsigned* Sfa  = (unsigned*)ws;
    short* WfaT    = (short*)(ws + SFA_B);
    short* WrT     = (short*)(ws + SFA_B + 16384);
    float* bis_enc = (float*)(ws + SFA_B + 32768);
    float* bisg    = (float*)(ws + SFA_B + 33280);
    float* cw      = (float*)(ws + SFA_B + 33792);

    pt_prep<<<dim3(32), dim3(256), 0, stream>>>(
        Wf, Wa, Wr, Wx, fg, fb, fm, fv, ag, ab, am, av,
        xg, xb, xm, xv, rg, rb, rm, rv, WfaT, WrT, bis_enc, bisg, cw);
    pt_encode3<<<dim3(Bc * Nc / 64), dim3(256), 0, stream>>>(
        feats, xyz, WfaT, bis_enc, cw, Sfa);
    pt_gr4<<<dim3((Bc * Mc) / 8), dim3(512), 0, stream>>>(
        nxyz, Sfa, WrT, bisg, cw, gidx, gcnt, out);
}

// Round 8
// 34.197 us; speedup vs baseline: 7.6177x; 1.2946x over previous
//
#include <hip/hip_runtime.h>

constexpr int Bc = 4, Nc = 16384, Mc = 4096, Kc = 32;
constexpr float EPSc = 1e-5f;
constexpr float L2E = 1.4426950408889634f;   // log2(e)

using bf16x8 = __attribute__((ext_vector_type(8))) short;   // 8 bf16 (4 VGPRs)
using f32x4  = __attribute__((ext_vector_type(4))) float;   // 4 fp32

__device__ inline unsigned f2bf_bits(float x) {
    unsigned u = __float_as_uint(x);
    return (u + 0x7fffu + ((u >> 16) & 1u)) >> 16;
}
__device__ inline short f2bf(float x) { return (short)f2bf_bits(x); }

// ---------------------------------------------------------------------------
// pt_enc (MFMA): Sfa[n][c] = pack( hi = bf16((f_bn + dot(x_n,w_c))*log2e),
//                                  lo = bf16(a_bn + dot(x_n,w_c)) )
// Self-contained: stages scaled bf16 W^T per block (fixed-channel-per-thread,
// scale computed in registers), folds the neighbor xyz term, writes C through
// an LDS transpose tile -> 16 coalesced 256B row stores per wave.
// ---------------------------------------------------------------------------
__global__ __launch_bounds__(256) void pt_enc(
    const float* __restrict__ feats, const float* __restrict__ xyz,
    const float* __restrict__ Wf, const float* __restrict__ Wa,
    const float* __restrict__ Wx,
    const float* __restrict__ fg, const float* __restrict__ fb,
    const float* __restrict__ fm, const float* __restrict__ fv,
    const float* __restrict__ ag, const float* __restrict__ ab,
    const float* __restrict__ am, const float* __restrict__ av,
    const float* __restrict__ xg, const float* __restrict__ xb,
    const float* __restrict__ xm, const float* __restrict__ xv,
    unsigned* __restrict__ Sfa)
{
    __shared__ __align__(16) short WT[128][72];   // [col][k]
    __shared__ unsigned stile[4][16][68];         // transpose tile per wave
    __shared__ float  sx[64][3];                  // block's 64 points' xyz
    __shared__ float4 scw[64];                    // per-channel {w0,w1,w2,-}
    __shared__ float  bis[128];

    const int tid = threadIdx.x, lane = tid & 63, w = tid >> 6;
    const int row16 = lane & 15, kg = lane >> 4;
    const long long row0 = (long long)blockIdx.x * 64;

    if (tid < 192) ((float*)sx)[tid] = xyz[row0 * 3 + tid];
    if (tid < 64) {
        const float xs = xg[tid] * rsqrtf(xv[tid] + EPSc);
        scw[tid] = make_float4(Wx[tid] * xs, Wx[64 + tid] * xs,
                               Wx[128 + tid] * xs, 0.f);
    }
    if (tid < 128) {
        const int c = tid & 63;
        const float g  = (tid < 64) ? fg[c] : ag[c];
        const float v  = (tid < 64) ? fv[c] : av[c];
        const float bb = (tid < 64) ? fb[c] : ab[c];
        const float mm = (tid < 64) ? fm[c] : am[c];
        const float s = g * rsqrtf(v + EPSc);
        bis[tid] = (tid < 64) ? (bb - mm * s) * L2E : (bb - mm * s);
    }
    {   // WT staging: thread owns channel c = tid&63 for both planes
        const int c = tid & 63, k0 = tid >> 6;
        const float sf = fg[c] * rsqrtf(fv[c] + EPSc) * L2E;
        const float sa = ag[c] * rsqrtf(av[c] + EPSc);
#pragma unroll
        for (int it = 0; it < 16; ++it) {
            const int k = k0 + 4 * it;
            WT[c][k]      = f2bf(Wf[k * 64 + c] * sf);
            WT[64 + c][k] = f2bf(Wa[k * 64 + c] * sa);
        }
    }
    __syncthreads();

    bf16x8 bfr[8][2];
#pragma unroll
    for (int t = 0; t < 8; ++t)
#pragma unroll
        for (int h = 0; h < 2; ++h)
            bfr[t][h] = *(const bf16x8*)&WT[16 * t + row16][32 * h + kg * 8];

    const long long base = row0 + w * 16;
    const float* arow = feats + (base + row16) * 64 + kg * 8;
    const float4 v0 = *(const float4*)(arow + 0);
    const float4 v1 = *(const float4*)(arow + 4);
    const float4 v2 = *(const float4*)(arow + 32);
    const float4 v3 = *(const float4*)(arow + 36);
    bf16x8 af0, af1;
    af0[0]=f2bf(v0.x); af0[1]=f2bf(v0.y); af0[2]=f2bf(v0.z); af0[3]=f2bf(v0.w);
    af0[4]=f2bf(v1.x); af0[5]=f2bf(v1.y); af0[6]=f2bf(v1.z); af0[7]=f2bf(v1.w);
    af1[0]=f2bf(v2.x); af1[1]=f2bf(v2.y); af1[2]=f2bf(v2.z); af1[3]=f2bf(v2.w);
    af1[4]=f2bf(v3.x); af1[5]=f2bf(v3.y); af1[6]=f2bf(v3.z); af1[7]=f2bf(v3.w);

    f32x4 acc[8];
#pragma unroll
    for (int t = 0; t < 8; ++t) {
        f32x4 z = {0.f, 0.f, 0.f, 0.f};
        z = __builtin_amdgcn_mfma_f32_16x16x32_bf16(af0, bfr[t][0], z, 0, 0, 0);
        z = __builtin_amdgcn_mfma_f32_16x16x32_bf16(af1, bfr[t][1], z, 0, 0, 0);
        acc[t] = z;
    }

    // per-lane xyz-proj coeffs for this lane's 4 output cols
    float4 cwt[4];
#pragma unroll
    for (int t = 0; t < 4; ++t)
        cwt[t] = scw[16 * t + row16];

    const int lrow = w * 16 + kg * 4;
    // C/D layout: row=(lane>>4)*4+reg, col=lane&15 -> LDS tile -> coalesced
#pragma unroll
    for (int r = 0; r < 4; ++r) {
        const float x0 = sx[lrow + r][0], x1 = sx[lrow + r][1], x2 = sx[lrow + r][2];
#pragma unroll
        for (int t = 0; t < 4; ++t) {
            const int c = 16 * t + row16;
            const float px = fmaf(x0, cwt[t].x, fmaf(x1, cwt[t].y, x2 * cwt[t].z));
            stile[w][kg * 4 + r][c] =
                  f2bf_bits(acc[t + 4][r] + bis[64 + c] + px)
                | (f2bf_bits(acc[t][r] + bis[c] + px * L2E) << 16);
        }
    }
    __syncthreads();
#pragma unroll
    for (int rr = 0; rr < 16; ++rr)
        Sfa[(base + rr) * 64 + lane] = stile[w][rr][lane];
}

// ---------------------------------------------------------------------------
// pt_gr5: 512 thr = 8 waves, 2 groups/wave (16/block), 1024 blocks.
// Neighbor lists live in ONE register per wave (64 coalesced ints); readlane
// puts each index in an SGPR -> gather addressing is pure SALU. No barrier
// before the gather loop; WT staging overlaps gather latency. Single
// __syncthreads before the refine MFMA. XCD-pinned swizzle (batch->XCD pair).
// ---------------------------------------------------------------------------
__global__ __launch_bounds__(512) void pt_gr5(
    const float* __restrict__ nxyz, const unsigned* __restrict__ Sfa,
    const float* __restrict__ Wr,
    const float* __restrict__ rg, const float* __restrict__ rb,
    const float* __restrict__ rm, const float* __restrict__ rv,
    const float* __restrict__ Wx,
    const float* __restrict__ xg, const float* __restrict__ xb,
    const float* __restrict__ xm, const float* __restrict__ xv,
    const int* __restrict__ gidx, const int* __restrict__ gcnt,
    float* __restrict__ out)
{
    __shared__ __align__(16) short WT[128][72];   // refine weights [col][k]
    __shared__ __align__(16) short snf[16][72];   // softmax outputs [group][ch]

    const int tid = threadIdx.x, lane = tid & 63, w = tid >> 6;
    const int row16 = lane & 15, kg = lane >> 4;
    // bijective XCD-pinning swizzle: xcd = blk%8 serves batch (blk%8)>>1
    const int i = blockIdx.x;                     // 0..1023
    const int b = (i & 7) >> 1;
    const int j = ((i >> 3) << 1) | (i & 1);      // 0..255
    const long long gbase = (long long)b * Mc + j * 16;

    // both groups' neighbor lists in one coalesced 64-int load (wave-local)
    const int nv = gidx[(gbase + 2 * w) * 32 + lane];

    {   // WT staging: thread owns channel c = tid&127 (scale in registers)
        const int c = tid & 127, k0 = tid >> 7;
        const float sr = rg[c] * rsqrtf(rv[c] + EPSc);
#pragma unroll
        for (int it = 0; it < 16; ++it) {
            const int k = k0 + 4 * it;
            WT[c][k] = f2bf(Wr[k * 128 + c] * sr);
        }
    }

    // per-lane channel coeffs (channel = lane) + per-group constants
    const float xs = xg[lane] * rsqrtf(xv[lane] + EPSc);
    const float w0 = Wx[lane] * xs, w1 = Wx[64 + lane] * xs, w2 = Wx[128 + lane] * xs;
    const float P = xb[lane] - xm[lane] * xs;
    const float* nx = nxyz + (gbase + 2 * w) * 3;  // 6 floats = both groups
    const float QA = P - fmaf(nx[0], w0, fmaf(nx[1], w1, nx[2] * w2));
    const float QB = P - fmaf(nx[3], w0, fmaf(nx[4], w1, nx[5] * w2));
    const float QlA = QA * L2E, QlB = QB * L2E;

    const unsigned* sbase = Sfa + (long long)b * (Nc * 64) + lane;
    float ssA = 0.f, acA = 0.f, ssB = 0.f, acB = 0.f;
#pragma unroll
    for (int k = 0; k < Kc; ++k) {
        const int nA = __builtin_amdgcn_readlane(nv, k);        // SGPR index
        const int nB = __builtin_amdgcn_readlane(nv, 32 + k);
        const unsigned dA = sbase[nA << 6];        // SALU-addressed 256B gather
        const unsigned dB = sbase[nB << 6];
        const float eA = __builtin_amdgcn_exp2f(__uint_as_float(dA & 0xffff0000u) + QlA);
        const float aA = __uint_as_float(dA << 16) + QA;
        const float eB = __builtin_amdgcn_exp2f(__uint_as_float(dB & 0xffff0000u) + QlB);
        const float aB = __uint_as_float(dB << 16) + QB;
        ssA += eA; acA = fmaf(eA, aA, acA);
        ssB += eB; acB = fmaf(eB, aB, acB);
    }
    snf[2 * w][lane]     = f2bf(acA * __builtin_amdgcn_rcpf(ssA));
    snf[2 * w + 1][lane] = f2bf(acB * __builtin_amdgcn_rcpf(ssB));
    __syncthreads();

    // refine MFMA: A = snf (16 rows), B = WT col-tile w
    const bf16x8 af0 = *(const bf16x8*)&snf[row16][kg * 8];
    const bf16x8 af1 = *(const bf16x8*)&snf[row16][32 + kg * 8];
    const bf16x8 bf0 = *(const bf16x8*)&WT[16 * w + row16][kg * 8];
    const bf16x8 bf1 = *(const bf16x8*)&WT[16 * w + row16][32 + kg * 8];
    f32x4 z = {0.f, 0.f, 0.f, 0.f};
    z = __builtin_amdgcn_mfma_f32_16x16x32_bf16(af0, bf0, z, 0, 0, 0);
    z = __builtin_amdgcn_mfma_f32_16x16x32_bf16(af1, bf1, z, 0, 0, 0);

    // epilogue: BN+ReLU+mask; per-lane channel cc fixed -> scale in registers
    const int4 c4 = *(const int4*)(gcnt + gbase + kg * 4);
    const int cc = 16 * w + row16;
    const float sr = rg[cc] * rsqrtf(rv[cc] + EPSc);
    const float bb = rb[cc] - rm[cc] * sr;
    float* orow = out + (gbase + kg * 4) * 128 + cc;
    __builtin_nontemporal_store(fmaxf(z[0] + bb, 0.f) * (c4.x > 0 ? 1.f : 0.f), orow);
    __builtin_nontemporal_store(fmaxf(z[1] + bb, 0.f) * (c4.y > 0 ? 1.f : 0.f), orow + 128);
    __builtin_nontemporal_store(fmaxf(z[2] + bb, 0.f) * (c4.z > 0 ? 1.f : 0.f), orow + 256);
    __builtin_nontemporal_store(fmaxf(z[3] + bb, 0.f) * (c4.w > 0 ? 1.f : 0.f), orow + 384);
}

extern "C" void kernel_launch(void* const* d_in, const int* in_sizes, int n_in,
                              void* d_out, int out_size, void* d_ws, size_t ws_size,
                              hipStream_t stream)
{
    const float* xyz  = (const float*)d_in[0];
    const float* nxyz = (const float*)d_in[1];
    const float* feats = (const float*)d_in[2];
    const float* Wf = (const float*)d_in[3];
    const float* fg = (const float*)d_in[4];
    const float* fb = (const float*)d_in[5];
    const float* fm = (const float*)d_in[6];
    const float* fv = (const float*)d_in[7];
    const float* Wa = (const float*)d_in[8];
    const float* ag = (const float*)d_in[9];
    const float* ab = (const float*)d_in[10];
    const float* am = (const float*)d_in[11];
    const float* av = (const float*)d_in[12];
    const float* Wx = (const float*)d_in[13];
    const float* xg = (const float*)d_in[14];
    const float* xb = (const float*)d_in[15];
    const float* xm = (const float*)d_in[16];
    const float* xv = (const float*)d_in[17];
    const float* Wr = (const float*)d_in[18];
    const float* rg = (const float*)d_in[19];
    const float* rb = (const float*)d_in[20];
    const float* rm = (const float*)d_in[21];
    const float* rv = (const float*)d_in[22];
    const int* gidx = (const int*)d_in[23];
    const int* gcnt = (const int*)d_in[24];
    float* out = (float*)d_out;

    unsigned* Sfa = (unsigned*)d_ws;   // B*N*64 dwords = 16 MiB packed bf16 pairs

    pt_enc<<<dim3(Bc * Nc / 64), dim3(256), 0, stream>>>(
        feats, xyz, Wf, Wa, Wx,
        fg, fb, fm, fv, ag, ab, am, av, xg, xb, xm, xv, Sfa);
    pt_gr5<<<dim3((Bc * Mc) / 16), dim3(512), 0, stream>>>(
        nxyz, Sfa, Wr, rg, rb, rm, rv, Wx, xg, xb, xm, xv,
        gidx, gcnt, out);
}